// Round 4
// baseline (320.187 us; speedup 1.0000x reference)
//
#include <hip/hip_runtime.h>
#include <math.h>

// SingleRoIExtractor: 4-level FPN RoIAlign (mmdet legacy, aligned=False)
// R4: separable-bilinear direct gather. R3 evidence: both LDS-staged and
// naive-gather converge at ~150us with NO pipe saturated (VALU 14%, HBM 37%,
// LDS 0, occ 57%) -> per-CU vector-memory transaction pipe is the limiter
// (~22 line-lookups per load instr x 16 instrs/ch, 358k cycles matches).
// Fix: out = sum_r wy_r * dot(row_r, wx) -- the x-profile wx (<=4 nonzeros
// at cx0,cx0+1,cx1,cx1+1, validity folded in) is IDENTICAL for all rows, so
// per channel each lane does ONE aligned float4 load per needed row
// (+ masked 2nd quad for wide bins, + masked 1-dword fixup when a pair
// straddles the quad). Rows 3/4 exec-masked off when narrow bins duplicate
// them (dy<2 / dy<1). 16 load-instrs/ch -> ~4 + sparse extras; each unique
// line looked up ~once instead of 3-4x.
// All weights/offsets built once per lane; channel loop is loads+FMAs only.
// Masked loads are `cond ? load : 0` (never multiply stale regs).
// Level 3 (W=38, 8B alignment) uses float2 quads via the same template.
// No LDS, no barriers; lanes >= 49 exit immediately.

#define OUT_SZ 7
#define NCH 256
#define NBINS 49
#define NGROUPS 4

template<int A>   // A = floats per aligned vector chunk (4 for lvl0-2, 2 for lvl3)
__device__ __forceinline__ void roi_gather(
    const float* __restrict__ chp, float* __restrict__ outp,
    int W, int H, size_t chstep,
    float x1, float y1, float bw, float bh, int oy, int ox)
{
    const float fH = (float)H, fW = (float)W;

    // ---- x geometry (2 sub-samples) ----
    float lxv[2], fxv[2]; int cxv[2];
#pragma unroll
    for (int j = 0; j < 2; ++j) {
        float xs = x1 + ((float)(2 * ox + j) + 0.5f) * 0.5f * bw;
        fxv[j] = (xs >= -1.0f && xs <= fW) ? 1.0f : 0.0f;
        float xc = fminf(fmaxf(xs, 0.0f), fW - 1.0f);
        int x0 = (int)floorf(xc);
        x0 = min(x0, W - 2);            // xc=W-1 -> lx=1.0 selects col W-1
        lxv[j] = xc - (float)x0;
        cxv[j] = x0;
    }
    // ---- y geometry ----
    float lyv[2], fyv[2]; int ryv[2];
#pragma unroll
    for (int i = 0; i < 2; ++i) {
        float ys = y1 + ((float)(2 * oy + i) + 0.5f) * 0.5f * bh;
        fyv[i] = (ys >= -1.0f && ys <= fH) ? 1.0f : 0.0f;
        float yc = fminf(fmaxf(ys, 0.0f), fH - 1.0f);
        int y0 = (int)floorf(yc);
        y0 = min(y0, H - 2);            // yc=H-1 -> ly=1.0 selects row H-1
        lyv[i] = yc - (float)y0;
        ryv[i] = y0;
    }

    // ---- x profile -> weights for (quadA, quadB, fix0, fix1) ----
    // Contributions: c00@cx0, c01@cx0+1, c10@cx1, c11@cx1+1. Each assigned
    // to exactly one load slot. quadA at a0 (always), quadB at a1 (wide
    // bins), fix0 = dword at a0+A (pair straddle), fix1 = dword at a1+A.
    const int i00 = cxv[0] & (A - 1), i01 = cxv[1] & (A - 1);
    const int a0  = cxv[0] - i00,     a1  = cxv[1] - i01;
    const bool sq  = (a1 == a0);
    const bool of0 = (i00 == A - 1);
    const bool of1 = (i01 == A - 1);
    const float c00 = fxv[0] * (1.0f - lxv[0]), c01 = fxv[0] * lxv[0];
    const float c10 = fxv[1] * (1.0f - lxv[1]), c11 = fxv[1] * lxv[1];

    float wA[A], wB[A];
#pragma unroll
    for (int m = 0; m < A; ++m) {
        float v = 0.0f;
        v += (i00 == m) ? c00 : 0.0f;
        v += (!of0 && (i00 + 1 == m)) ? c01 : 0.0f;
        v += (sq && (i01 == m)) ? c10 : 0.0f;
        v += (sq && !of1 && (i01 + 1 == m)) ? c11 : 0.0f;
        wA[m] = v;
        wB[m] = (!sq) ? (((i01 == m) ? c10 : 0.0f) +
                         ((!of1 && (i01 + 1 == m)) ? c11 : 0.0f))
                      : 0.0f;
    }
    const float wf0 = (of0 ? c01 : 0.0f) + ((sq && of1) ? c11 : 0.0f);
    const float wf1 = (!sq && of1) ? c11 : 0.0f;
    const bool useB  = !sq;
    const bool useF0 = of0 || (sq && of1);
    const bool useF1 = !sq && of1;

    // ---- y profile -> 4 row slots, duplicates merged ----
    // Rows ry0, ry0+1, ry1, ry1+1; when dy=ry1-ry0 is 0/1 the j=1 sample's
    // rows coincide with slot 0/1 and their weights fold in; the redundant
    // slots get weight 0 and their loads are exec-masked off.
    const int dy = ryv[1] - ryv[0];
    const float wy0 = fyv[0] * (1.0f - lyv[0]) +
                      ((dy == 0) ? fyv[1] * (1.0f - lyv[1]) : 0.0f);
    const float wy1 = fyv[0] * lyv[0] +
                      ((dy == 0) ? fyv[1] * lyv[1]
                                 : ((dy == 1) ? fyv[1] * (1.0f - lyv[1]) : 0.0f));
    const float wy2 = (dy >= 2) ? fyv[1] * (1.0f - lyv[1]) : 0.0f;
    const float wy3 = (dy >= 1) ? fyv[1] * lyv[1] : 0.0f;

    const float wys[4] = {wy0, wy1, wy2, wy3};
    int offA[4], offB[4];
    {
        const int rows0 = ryv[0], rows1 = ryv[0] + 1;
        const int rows2 = ryv[1], rows3 = ryv[1] + 1;   // all <= H-1
        offA[0] = rows0 * W + a0;  offB[0] = rows0 * W + a1;
        offA[1] = rows1 * W + a0;  offB[1] = rows1 * W + a1;
        offA[2] = rows2 * W + a0;  offB[2] = rows2 * W + a1;
        offA[3] = rows3 * W + a0;  offB[3] = rows3 * W + a1;
    }

    // ---- channel loop: this wave's 16 channels (stride 4) ----
    const float* p = chp;
    float* o = outp;
    for (int c = 0; c < 16; ++c) {
        float acc = 0.0f;
#pragma unroll
        for (int r = 0; r < 4; ++r) {
            const float wy = wys[r];
            const bool rv = (wy != 0.0f);
            float qa[A], qb[A];
            if (A == 4) {
                float4 va = rv ? *(const float4*)(p + offA[r])
                               : make_float4(0.f, 0.f, 0.f, 0.f);
                qa[0] = va.x; qa[1] = va.y; qa[2] = va.z; qa[3] = va.w;
                float4 vb = (rv && useB) ? *(const float4*)(p + offB[r])
                                         : make_float4(0.f, 0.f, 0.f, 0.f);
                qb[0] = vb.x; qb[1] = vb.y; qb[2] = vb.z; qb[3] = vb.w;
            } else {
                float2 va = rv ? *(const float2*)(p + offA[r])
                               : make_float2(0.f, 0.f);
                qa[0] = va.x; qa[1] = va.y;
                float2 vb = (rv && useB) ? *(const float2*)(p + offB[r])
                                         : make_float2(0.f, 0.f);
                qb[0] = vb.x; qb[1] = vb.y;
            }
            float f0 = (rv && useF0) ? p[offA[r] + A] : 0.0f;
            float f1 = (rv && useF1) ? p[offB[r] + A] : 0.0f;
            float h = f0 * wf0 + f1 * wf1;
#pragma unroll
            for (int m = 0; m < A; ++m)
                h += qa[m] * wA[m] + qb[m] * wB[m];
            acc += wy * h;
        }
        *o = acc * 0.25f;
        p += chstep;
        o += 4 * NBINS;
    }
}

__global__ __launch_bounds__(256, 6)
void roi_align_sep(const float* __restrict__ f0, const float* __restrict__ f1,
                   const float* __restrict__ f2, const float* __restrict__ f3,
                   const float* __restrict__ rois,
                   float* __restrict__ out)
{
    const int k = blockIdx.x;
    const int g = blockIdx.y;
    const int t = threadIdx.x;
    const int w    = t >> 6;   // wave id 0..3
    const int lane = t & 63;

    float rb   = rois[k * 5 + 0];
    float rix1 = rois[k * 5 + 1];
    float riy1 = rois[k * 5 + 2];
    float rix2 = rois[k * 5 + 3];
    float riy2 = rois[k * 5 + 4];

    float scale = sqrtf((rix2 - rix1 + 1.0f) * (riy2 - riy1 + 1.0f));
    int lvl = (int)floorf(log2f(scale * (1.0f / 56.0f) + 1e-6f));
    lvl = lvl < 0 ? 0 : (lvl > 3 ? 3 : lvl);

    float ss = 1.0f / (float)(4 << lvl);
    float x1 = rix1 * ss, y1 = riy1 * ss;
    float rw = fmaxf(rix2 * ss - x1, 1.0f);
    float rh = fmaxf(riy2 * ss - y1, 1.0f);
    float bw = rw * (1.0f / OUT_SZ);
    float bh = rh * (1.0f / OUT_SZ);
    const int H = 800  >> (2 + lvl);
    const int W = 1216 >> (2 + lvl);

    const float* fb = (lvl == 0) ? f0 : (lvl == 1) ? f1 : (lvl == 2) ? f2 : f3;
    const int HW = H * W;

    if (lane >= NBINS) return;   // no barriers anywhere -> safe
    const int bin = lane;
    const int oy = bin / OUT_SZ;
    const int ox = bin - oy * OUT_SZ;

    const int ch0 = g * 64 + w;          // this wave's first channel
    const float* chp = fb + (size_t)((int)rb * NCH + ch0) * HW;
    float* outp = out + ((size_t)k * NCH + ch0) * NBINS + bin;

    if (W & 3) {   // level 3: W=38, rows only 8B-aligned -> float2 chunks
        roi_gather<2>(chp, outp, W, H, 4 * (size_t)HW, x1, y1, bw, bh, oy, ox);
    } else {       // levels 0-2: 16B-aligned float4 chunks
        roi_gather<4>(chp, outp, W, H, 4 * (size_t)HW, x1, y1, bw, bh, oy, ox);
    }
}

extern "C" void kernel_launch(void* const* d_in, const int* in_sizes, int n_in,
                              void* d_out, int out_size, void* d_ws, size_t ws_size,
                              hipStream_t stream)
{
    const float* f0   = (const float*)d_in[0];
    const float* f1   = (const float*)d_in[1];
    const float* f2   = (const float*)d_in[2];
    const float* f3   = (const float*)d_in[3];
    const float* rois = (const float*)d_in[4];
    float* out = (float*)d_out;

    int K = in_sizes[4] / 5;
    if (K <= 0) return;

    roi_align_sep<<<dim3(K, NGROUPS), 256, 0, stream>>>(f0, f1, f2, f3, rois, out);
}